// Round 3
// baseline (466.597 us; speedup 1.0000x reference)
//
#include <hip/hip_runtime.h>
#include <stdint.h>

#define B_ROWS 16384
#define NF 26
#define NV 100000
#define NN 13
#define ND 32
#define K1DIM 1248   // (26+13)*32
#define H1DIM 256
#define H2DIM 128
#define H3DIM 64

typedef float f32x4 __attribute__((ext_vector_type(4)));
typedef short bf16x8 __attribute__((ext_vector_type(8)));

static __device__ __forceinline__ unsigned short f2bf(float f) {
    unsigned int u = __float_as_uint(f);
    unsigned int r = (u + 0x7fffu + ((u >> 16) & 1u)) >> 16;
    return (unsigned short)r;
}

static __device__ __forceinline__ void store_bf4(unsigned short* p, f32x4 e) {
    uint2 u;
    u.x = (unsigned)f2bf(e.x) | ((unsigned)f2bf(e.y) << 16);
    u.y = (unsigned)f2bf(e.z) | ((unsigned)f2bf(e.w) << 16);
    *(uint2*)p = u;
}

// ---------------- sizes for weight repack fp32 (K,N) -> bf16 packed [kt][n][kk] ----------------
#define S1P ((K1DIM/32)*H1DIM*32)   // 319488
#define S2P ((H1DIM/32)*H2DIM*32)   // 32768
#define S3P ((H2DIM/32)*H3DIM*32)   // 8192
#define EMB_BLOCKS 512              // 32 rows per block
#define RPK_BLOCKS ((S1P + S2P + S3P) / 256)   // 1408

// ---------------- fused: embedding gather + FM + linear  AND  weight repack ----------------
// blocks [0, EMB_BLOCKS): embed path, 8 lanes x float4 per row, 8 rows/wave, 32 rows/block.
// blocks [EMB_BLOCKS, EMB_BLOCKS+RPK_BLOCKS): weight repack path.
__global__ __launch_bounds__(256) void prep(
    const int* __restrict__ x_cat, const float* __restrict__ x_num,
    const float* __restrict__ emb0, const float* __restrict__ emb1,
    const float* __restrict__ num_bias, const float* __restrict__ num_emb,
    const float* __restrict__ W1, const float* __restrict__ W2, const float* __restrict__ W3,
    unsigned short* __restrict__ Xp, float* __restrict__ lin_out, float* __restrict__ fm_out,
    unsigned short* __restrict__ W1p, unsigned short* __restrict__ W2p, unsigned short* __restrict__ W3p)
{
    if (blockIdx.x >= EMB_BLOCKS) {
        int tid = (blockIdx.x - EMB_BLOCKS) * 256 + threadIdx.x;
        if (tid < S1P) {
            int kk = tid & 31; int n = (tid >> 5) & (H1DIM - 1); int kt = tid >> 13;
            W1p[tid] = f2bf(W1[(kt * 32 + kk) * H1DIM + n]);
        } else if (tid < S1P + S2P) {
            int t = tid - S1P;
            int kk = t & 31; int n = (t >> 5) & (H2DIM - 1); int kt = t >> 12;
            W2p[t] = f2bf(W2[(kt * 32 + kk) * H2DIM + n]);
        } else {
            int t = tid - S1P - S2P;
            int kk = t & 31; int n = (t >> 5) & (H3DIM - 1); int kt = t >> 11;
            W3p[t] = f2bf(W3[(kt * 32 + kk) * H3DIM + n]);
        }
        return;
    }

    int sub = threadIdx.x & 7;                 // lane within row-group (covers dims sub*4..sub*4+3)
    int row = blockIdx.x * 32 + (threadIdx.x >> 3);
    int lanebase = (threadIdx.x & 63) & 56;    // base lane of this 8-lane row-group in the wave

    const int* xc = x_cat + row * NF;
    int idxh[4];
#pragma unroll
    for (int j = 0; j < 4; j++) { int f = sub + 8 * j; idxh[j] = (f < NF) ? xc[f] : 0; }
    float numh[2];
    numh[0] = x_num[row * NN + sub];
    numh[1] = (sub < NN - 8) ? x_num[row * NN + sub + 8] : 0.f;

    // linear-term partial for this lane's fields
    float lv = 0.f;
#pragma unroll
    for (int j = 0; j < 4; j++) { int f = sub + 8 * j; if (f < NF) lv += emb0[f * NV + idxh[j]]; }
    lv += numh[0] * num_bias[sub];
    if (sub < NN - 8) lv += numh[1] * num_bias[sub + 8];

    unsigned short* xr = Xp + (size_t)row * K1DIM;
    f32x4 s4 = (f32x4){0.f, 0.f, 0.f, 0.f};
    f32x4 q4 = (f32x4){0.f, 0.f, 0.f, 0.f};

#pragma unroll
    for (int f = 0; f < NF; ++f) {
        int idx = __shfl(idxh[f >> 3], lanebase + (f & 7), 64);
        f32x4 e = ((const f32x4*)(emb1 + (size_t)(f * NV + idx) * ND))[sub];
        s4 += e; q4 += e * e;
        store_bf4(xr + f * ND + sub * 4, e);
    }
#pragma unroll
    for (int n = 0; n < NN; ++n) {
        float xv = __shfl(numh[n >> 3], lanebase + (n & 7), 64);
        f32x4 w = ((const f32x4*)(num_emb + n * ND))[sub];
        f32x4 e = w * xv;
        s4 += e; q4 += e * e;
        store_bf4(xr + (NF + n) * ND + sub * 4, e);
    }

    float val = s4.x * s4.x + s4.y * s4.y + s4.z * s4.z + s4.w * s4.w
              - (q4.x + q4.y + q4.z + q4.w);
#pragma unroll
    for (int m = 1; m < 8; m <<= 1) {
        val += __shfl_xor(val, m, 64);
        lv  += __shfl_xor(lv,  m, 64);
    }
    if (sub == 0) { fm_out[row] = 0.5f * val; lin_out[row] = lv; }
}

// ---------------- bf16 MFMA GEMM + bias + relu -> bf16, software-pipelined ----------------
template<int TMM, int TMN>
__global__ __launch_bounds__(256) void gemm_relu(
    const unsigned short* __restrict__ X, const unsigned short* __restrict__ Wp,
    const float* __restrict__ bias, unsigned short* __restrict__ Y,
    int M, int N, int K)
{
    int wave = blockIdx.x * 4 + (threadIdx.x >> 6);
    int lane = threadIdx.x & 63;
    int l15 = lane & 15, quad = lane >> 4;
    int nWaveN = N / (16 * TMN);
    int wm = wave / nWaveN, wn = wave % nWaveN;
    int m0 = wm * 16 * TMM, n0 = wn * 16 * TMN;

    f32x4 acc[TMM][TMN];
#pragma unroll
    for (int i = 0; i < TMM; i++)
#pragma unroll
        for (int j = 0; j < TMN; j++) acc[i][j] = (f32x4){0.f, 0.f, 0.f, 0.f};

    const unsigned short* aptr = X + (size_t)(m0 + l15) * K + quad * 8;
    const unsigned short* bptr = Wp + ((size_t)n0 + l15) * 32 + quad * 8;
    const int KT = K >> 5;

    bf16x8 a[TMM], b[TMN];
#pragma unroll
    for (int i = 0; i < TMM; i++) a[i] = *(const bf16x8*)(aptr + (size_t)i * 16 * K);
#pragma unroll
    for (int j = 0; j < TMN; j++) b[j] = *(const bf16x8*)(bptr + (size_t)j * 16 * 32);

    for (int kt = 0; kt < KT - 1; ++kt) {
        bf16x8 an[TMM], bn[TMN];
        const unsigned short* ap = aptr + (size_t)(kt + 1) * 32;
        const unsigned short* bp = bptr + (size_t)(kt + 1) * N * 32;
#pragma unroll
        for (int i = 0; i < TMM; i++) an[i] = *(const bf16x8*)(ap + (size_t)i * 16 * K);
#pragma unroll
        for (int j = 0; j < TMN; j++) bn[j] = *(const bf16x8*)(bp + (size_t)j * 16 * 32);
#pragma unroll
        for (int i = 0; i < TMM; i++)
#pragma unroll
            for (int j = 0; j < TMN; j++)
                acc[i][j] = __builtin_amdgcn_mfma_f32_16x16x32_bf16(a[i], b[j], acc[i][j], 0, 0, 0);
#pragma unroll
        for (int i = 0; i < TMM; i++) a[i] = an[i];
#pragma unroll
        for (int j = 0; j < TMN; j++) b[j] = bn[j];
    }
#pragma unroll
    for (int i = 0; i < TMM; i++)
#pragma unroll
        for (int j = 0; j < TMN; j++)
            acc[i][j] = __builtin_amdgcn_mfma_f32_16x16x32_bf16(a[i], b[j], acc[i][j], 0, 0, 0);

#pragma unroll
    for (int j = 0; j < TMN; j++) {
        int col = n0 + j * 16 + l15;
        float bv = bias[col];
#pragma unroll
        for (int i = 0; i < TMM; i++) {
            int rbase = m0 + i * 16 + quad * 4;
#pragma unroll
            for (int r = 0; r < 4; r++) {
                float v = acc[i][j][r] + bv;
                v = v > 0.f ? v : 0.f;
                Y[(size_t)(rbase + r) * N + col] = f2bf(v);
            }
        }
    }
}

// ---------------- fused GEMM2 (256->128) + relu + GEMM3 (128->64) + relu + heads ----------------
#define LDP 136   // LDS row stride (shorts), padded from 128 to break bank conflicts
__global__ __launch_bounds__(256) void gemm23_head(
    const unsigned short* __restrict__ H1, const unsigned short* __restrict__ W2p,
    const float* __restrict__ b2,
    const unsigned short* __restrict__ W3p, const float* __restrict__ b3,
    const float* __restrict__ Wc, const float* __restrict__ bc,
    const float* __restrict__ Wo, const float* __restrict__ bo,
    const float* __restrict__ lin, const float* __restrict__ fm,
    float* __restrict__ out)
{
    __shared__ unsigned short lds[4 * 16 * LDP];
    int wid  = threadIdx.x >> 6;
    int wave = blockIdx.x * 4 + wid;
    int lane = threadIdx.x & 63;
    int l15 = lane & 15, quad = lane >> 4;
    int m0 = wave * 16;
    unsigned short* wlds = lds + wid * 16 * LDP;

    f32x4 acc2[8];
#pragma unroll
    for (int j = 0; j < 8; j++) acc2[j] = (f32x4){0.f, 0.f, 0.f, 0.f};

    const unsigned short* aptr = H1 + (size_t)(m0 + l15) * H1DIM + quad * 8;
    const unsigned short* bptr = W2p + l15 * 32 + quad * 8;
#pragma unroll
    for (int kt = 0; kt < 8; ++kt) {
        bf16x8 a = *(const bf16x8*)(aptr + kt * 32);
#pragma unroll
        for (int j = 0; j < 8; j++) {
            bf16x8 b = *(const bf16x8*)(bptr + (kt * H2DIM + j * 16) * 32);
            acc2[j] = __builtin_amdgcn_mfma_f32_16x16x32_bf16(a, b, acc2[j], 0, 0, 0);
        }
    }
#pragma unroll
    for (int j = 0; j < 8; j++) {
        int col = j * 16 + l15;
        float bv = b2[col];
#pragma unroll
        for (int r = 0; r < 4; r++) {
            float v = acc2[j][r] + bv;
            v = v > 0.f ? v : 0.f;
            wlds[(quad * 4 + r) * LDP + col] = f2bf(v);
        }
    }
    __syncthreads();

    f32x4 acc3[4];
#pragma unroll
    for (int j = 0; j < 4; j++) acc3[j] = (f32x4){0.f, 0.f, 0.f, 0.f};

    const unsigned short* b3ptr = W3p + l15 * 32 + quad * 8;
#pragma unroll
    for (int kt = 0; kt < 4; ++kt) {
        bf16x8 a = *(const bf16x8*)(wlds + l15 * LDP + kt * 32 + quad * 8);
#pragma unroll
        for (int j = 0; j < 4; j++) {
            bf16x8 b = *(const bf16x8*)(b3ptr + (kt * H3DIM + j * 16) * 32);
            acc3[j] = __builtin_amdgcn_mfma_f32_16x16x32_bf16(a, b, acc3[j], 0, 0, 0);
        }
    }

    float s1r[4] = {0.f, 0.f, 0.f, 0.f};
    float s2r[4] = {0.f, 0.f, 0.f, 0.f};
#pragma unroll
    for (int j = 0; j < 4; j++) {
        int col = j * 16 + l15;
        float bv = b3[col], wc = Wc[col], wo = Wo[col];
#pragma unroll
        for (int r = 0; r < 4; r++) {
            float v = acc3[j][r] + bv;
            v = v > 0.f ? v : 0.f;
            s1r[r] += v * wc;
            s2r[r] += v * wo;
        }
    }
#pragma unroll
    for (int r = 0; r < 4; r++) {
#pragma unroll
        for (int m = 8; m >= 1; m >>= 1) {
            s1r[r] += __shfl_xor(s1r[r], m, 16);
            s2r[r] += __shfl_xor(s2r[r], m, 16);
        }
    }
    if (l15 == 0) {
        float wc64 = Wc[64], wc65 = Wc[65], wo64 = Wo[64], wo65 = Wo[65];
        float bcv = bc[0], bov = bo[0];
#pragma unroll
        for (int r = 0; r < 4; r++) {
            int row = m0 + quad * 4 + r;
            float lt = lin[row], f2 = fm[row];
            out[row]          = s1r[r] + lt * wc64 + f2 * wc65 + bcv;
            out[B_ROWS + row] = s2r[r] + lt * wo64 + f2 * wo65 + bov;
        }
    }
}

// ---------------- workspace layout (bytes) ----------------
#define OFF_XP   ((size_t)0)
#define OFF_W1P  ((size_t)40894464)            // 16384*1248*2
#define OFF_W2P  (OFF_W1P + 638976)            // S1P*2
#define OFF_W3P  (OFF_W2P + 65536)             // S2P*2
#define OFF_H1   (OFF_W3P + 16384)             // S3P*2
#define OFF_LIN  (OFF_H1 + 8388608)            // 16384*256*2
#define OFF_FM   (OFF_LIN + 65536)
// total = OFF_FM + 65536 = 50135040 bytes (~50.1 MB)

extern "C" void kernel_launch(void* const* d_in, const int* in_sizes, int n_in,
                              void* d_out, int out_size, void* d_ws, size_t ws_size,
                              hipStream_t stream)
{
    const int*   x_cat    = (const int*)d_in[0];
    const float* x_num    = (const float*)d_in[1];
    const float* emb0     = (const float*)d_in[2];
    const float* emb1     = (const float*)d_in[3];
    const float* num_bias = (const float*)d_in[4];
    const float* num_emb  = (const float*)d_in[5];
    const float* W1 = (const float*)d_in[6];
    const float* b1 = (const float*)d_in[7];
    const float* W2 = (const float*)d_in[8];
    const float* b2 = (const float*)d_in[9];
    const float* W3 = (const float*)d_in[10];
    const float* b3 = (const float*)d_in[11];
    const float* Wc = (const float*)d_in[12];
    const float* bc = (const float*)d_in[13];
    const float* Wo = (const float*)d_in[14];
    const float* bo = (const float*)d_in[15];
    float* out = (float*)d_out;

    char* ws = (char*)d_ws;
    unsigned short* Xp  = (unsigned short*)(ws + OFF_XP);
    unsigned short* W1p = (unsigned short*)(ws + OFF_W1P);
    unsigned short* W2p = (unsigned short*)(ws + OFF_W2P);
    unsigned short* W3p = (unsigned short*)(ws + OFF_W3P);
    unsigned short* H1  = (unsigned short*)(ws + OFF_H1);
    float* lin = (float*)(ws + OFF_LIN);
    float* fm  = (float*)(ws + OFF_FM);

    // embed + FM + linear + weight repack, one launch
    prep<<<EMB_BLOCKS + RPK_BLOCKS, 256, 0, stream>>>(
        x_cat, x_num, emb0, emb1, num_bias, num_emb, W1, W2, W3,
        Xp, lin, fm, W1p, W2p, W3p);
    // L1: (16384,1248)@(1248,256): 32x32 per wave -> 4096 waves -> 1024 blocks (4 waves/SIMD)
    gemm_relu<2, 2><<<1024, 256, 0, stream>>>(Xp, W1p, b1, H1, B_ROWS, H1DIM, K1DIM);
    // L2+L3+heads fused: 16 rows per wave -> 1024 waves -> 256 blocks
    gemm23_head<<<B_ROWS / 16 / 4, 256, 0, stream>>>(H1, W2p, b2, W3p, b3, Wc, bc, Wo, bo, lin, fm, out);
}

// Round 4
// 435.896 us; speedup vs baseline: 1.0704x; 1.0704x over previous
//
#include <hip/hip_runtime.h>
#include <stdint.h>

#define B_ROWS 16384
#define NF 26
#define NV 100000
#define NN 13
#define ND 32
#define K1DIM 1248   // (26+13)*32
#define H1DIM 256
#define H2DIM 128
#define H3DIM 64

// LDS strides (shorts). Chosen so MFMA fragment reads are bank-conflict-free:
// XSTR: 1256 shorts = 628 dwords; 628 % 32 = 20 -> row-bases spread over 8 windows.
#define XSTR  1256
#define H1STR 264
#define H2STR 136
#define H2OFF (32 * H1STR)   // 8448 shorts; H2 region disjoint from H1, inside dead X

typedef float f32x4 __attribute__((ext_vector_type(4)));
typedef short bf16x8 __attribute__((ext_vector_type(8)));

static __device__ __forceinline__ unsigned short f2bf(float f) {
    unsigned int u = __float_as_uint(f);
    unsigned int r = (u + 0x7fffu + ((u >> 16) & 1u)) >> 16;
    return (unsigned short)r;
}

static __device__ __forceinline__ uint2 pack_bf4(f32x4 e) {
    uint2 u;
    u.x = (unsigned)f2bf(e.x) | ((unsigned)f2bf(e.y) << 16);
    u.y = (unsigned)f2bf(e.z) | ((unsigned)f2bf(e.w) << 16);
    return u;
}

// ---------------- repack W1/W2/W3 fp32 (K,N) -> bf16 packed [kt][n][kk] ----------------
#define S1P ((K1DIM/32)*H1DIM*32)   // 319488
#define S2P ((H1DIM/32)*H2DIM*32)   // 32768
#define S3P ((H2DIM/32)*H3DIM*32)   // 8192

__global__ __launch_bounds__(256) void repack_weights(
    const float* __restrict__ W1, const float* __restrict__ W2, const float* __restrict__ W3,
    unsigned short* __restrict__ W1p, unsigned short* __restrict__ W2p, unsigned short* __restrict__ W3p)
{
    int tid = blockIdx.x * 256 + threadIdx.x;
    if (tid < S1P) {
        int kk = tid & 31; int n = (tid >> 5) & (H1DIM - 1); int kt = tid >> 13;
        W1p[tid] = f2bf(W1[(kt * 32 + kk) * H1DIM + n]);
    } else if (tid < S1P + S2P) {
        int t = tid - S1P;
        int kk = t & 31; int n = (t >> 5) & (H2DIM - 1); int kt = t >> 12;
        W2p[t] = f2bf(W2[(kt * 32 + kk) * H2DIM + n]);
    } else if (tid < S1P + S2P + S3P) {
        int t = tid - S1P - S2P;
        int kk = t & 31; int n = (t >> 5) & (H3DIM - 1); int kt = t >> 11;
        W3p[t] = f2bf(W3[(kt * 32 + kk) * H3DIM + n]);
    }
}

// ---------------- fully fused DeepFM: gather+FM+linear -> MLP -> heads ----------------
// One block = 32 rows. 512 blocks. LDS: X tile 32x1256 shorts (78.5 KiB) -> 2 blocks/CU.
__global__ __launch_bounds__(256, 2) void deepfm_fused(
    const int* __restrict__ x_cat, const float* __restrict__ x_num,
    const float* __restrict__ emb0, const float* __restrict__ emb1,
    const float* __restrict__ num_bias, const float* __restrict__ num_emb,
    const unsigned short* __restrict__ W1p, const float* __restrict__ b1,
    const unsigned short* __restrict__ W2p, const float* __restrict__ b2,
    const unsigned short* __restrict__ W3p, const float* __restrict__ b3,
    const float* __restrict__ Wc, const float* __restrict__ bc,
    const float* __restrict__ Wo, const float* __restrict__ bo,
    float* __restrict__ out)
{
    __shared__ unsigned short Xs[32 * XSTR];
    __shared__ float s_fm[32], s_lin[32];

    const int tid  = threadIdx.x;
    const int wid  = tid >> 6;
    const int lane = tid & 63;
    const int l15  = lane & 15, quad = lane >> 4;
    const int row0 = blockIdx.x * 32;

    // ==== phase 0: embedding gather + FM second-order + linear term -> LDS ====
    {
        int sub  = tid & 7;            // covers dims sub*4 .. sub*4+3
        int rowL = tid >> 3;           // 0..31
        int row  = row0 + rowL;
        int lanebase = lane & 56;

        const int* xc = x_cat + row * NF;
        int idxh[4];
#pragma unroll
        for (int j = 0; j < 4; j++) { int f = sub + 8 * j; idxh[j] = (f < NF) ? xc[f] : 0; }
        float numh0 = x_num[row * NN + sub];
        float numh1 = (sub < NN - 8) ? x_num[row * NN + sub + 8] : 0.f;

        float lv = 0.f;
#pragma unroll
        for (int j = 0; j < 4; j++) { int f = sub + 8 * j; if (f < NF) lv += emb0[f * NV + idxh[j]]; }
        lv += numh0 * num_bias[sub];
        if (sub < NN - 8) lv += numh1 * num_bias[sub + 8];

        unsigned short* xr = &Xs[rowL * XSTR];
        f32x4 s4 = (f32x4){0.f, 0.f, 0.f, 0.f};
        f32x4 q4 = (f32x4){0.f, 0.f, 0.f, 0.f};
#pragma unroll
        for (int f = 0; f < NF; ++f) {
            int idx = __shfl(idxh[f >> 3], lanebase + (f & 7), 64);
            f32x4 e = ((const f32x4*)(emb1 + (size_t)(f * NV + idx) * ND))[sub];
            s4 += e; q4 += e * e;
            *(uint2*)(xr + f * ND + sub * 4) = pack_bf4(e);
        }
#pragma unroll
        for (int n = 0; n < NN; ++n) {
            float xv = __shfl((n < 8) ? numh0 : numh1, lanebase + (n & 7), 64);
            f32x4 w = ((const f32x4*)(num_emb + n * ND))[sub];
            f32x4 e = w * xv;
            s4 += e; q4 += e * e;
            *(uint2*)(xr + (NF + n) * ND + sub * 4) = pack_bf4(e);
        }
        float val = s4.x * s4.x + s4.y * s4.y + s4.z * s4.z + s4.w * s4.w
                  - (q4.x + q4.y + q4.z + q4.w);
#pragma unroll
        for (int m = 1; m < 8; m <<= 1) {
            val += __shfl_xor(val, m, 64);
            lv  += __shfl_xor(lv,  m, 64);
        }
        if (sub == 0) { s_fm[rowL] = 0.5f * val; s_lin[rowL] = lv; }
    }
    __syncthreads();

    // ==== phase 1: GEMM1 (32 x 1248) @ (1248 x 256), wave handles 32 rows x 64 cols ====
    f32x4 acc1[2][4];
#pragma unroll
    for (int i = 0; i < 2; i++)
#pragma unroll
        for (int j = 0; j < 4; j++) acc1[i][j] = (f32x4){0.f, 0.f, 0.f, 0.f};

    {
        const unsigned short* bptr = W1p + ((size_t)(wid * 64) + l15) * 32 + quad * 8;
        const unsigned short* abase = &Xs[l15 * XSTR + quad * 8];
        const int KT = K1DIM / 32;   // 39

        bf16x8 a[2], b[4];
#pragma unroll
        for (int i = 0; i < 2; i++) a[i] = *(const bf16x8*)(abase + i * 16 * XSTR);
#pragma unroll
        for (int j = 0; j < 4; j++) b[j] = *(const bf16x8*)(bptr + j * 512);

        for (int kt = 0; kt < KT - 1; ++kt) {
            bf16x8 an[2], bn[4];
            const unsigned short* ap = abase + (kt + 1) * 32;
            const unsigned short* bp = bptr + (size_t)(kt + 1) * (H1DIM * 32);
#pragma unroll
            for (int i = 0; i < 2; i++) an[i] = *(const bf16x8*)(ap + i * 16 * XSTR);
#pragma unroll
            for (int j = 0; j < 4; j++) bn[j] = *(const bf16x8*)(bp + j * 512);
#pragma unroll
            for (int i = 0; i < 2; i++)
#pragma unroll
                for (int j = 0; j < 4; j++)
                    acc1[i][j] = __builtin_amdgcn_mfma_f32_16x16x32_bf16(a[i], b[j], acc1[i][j], 0, 0, 0);
#pragma unroll
            for (int i = 0; i < 2; i++) a[i] = an[i];
#pragma unroll
            for (int j = 0; j < 4; j++) b[j] = bn[j];
        }
#pragma unroll
        for (int i = 0; i < 2; i++)
#pragma unroll
            for (int j = 0; j < 4; j++)
                acc1[i][j] = __builtin_amdgcn_mfma_f32_16x16x32_bf16(a[i], b[j], acc1[i][j], 0, 0, 0);
    }
    __syncthreads();   // all waves done reading X -> safe to overwrite with H1

    // relu+bias -> H1 tile (32 x 256, stride H1STR) at LDS offset 0
#pragma unroll
    for (int j = 0; j < 4; j++) {
        int col = wid * 64 + j * 16 + l15;
        float bv = b1[col];
#pragma unroll
        for (int i = 0; i < 2; i++) {
#pragma unroll
            for (int r = 0; r < 4; r++) {
                float v = acc1[i][j][r] + bv;
                v = v > 0.f ? v : 0.f;
                Xs[(i * 16 + quad * 4 + r) * H1STR + col] = f2bf(v);
            }
        }
    }
    __syncthreads();

    // ==== phase 2: GEMM2 (32 x 256) @ (256 x 128), wave handles 32 rows x 32 cols ====
    f32x4 acc2[2][2];
#pragma unroll
    for (int i = 0; i < 2; i++)
#pragma unroll
        for (int j = 0; j < 2; j++) acc2[i][j] = (f32x4){0.f, 0.f, 0.f, 0.f};
    {
        const unsigned short* bptr = W2p + ((size_t)(wid * 32) + l15) * 32 + quad * 8;
        const unsigned short* abase = &Xs[l15 * H1STR + quad * 8];
#pragma unroll
        for (int kt = 0; kt < 8; ++kt) {
            bf16x8 a[2], b[2];
#pragma unroll
            for (int i = 0; i < 2; i++) a[i] = *(const bf16x8*)(abase + i * 16 * H1STR + kt * 32);
#pragma unroll
            for (int j = 0; j < 2; j++) b[j] = *(const bf16x8*)(bptr + (size_t)kt * (H2DIM * 32) + j * 512);
#pragma unroll
            for (int i = 0; i < 2; i++)
#pragma unroll
                for (int j = 0; j < 2; j++)
                    acc2[i][j] = __builtin_amdgcn_mfma_f32_16x16x32_bf16(a[i], b[j], acc2[i][j], 0, 0, 0);
        }
    }
    // relu+bias -> H2 tile (32 x 128, stride H2STR) at LDS offset H2OFF (disjoint from H1)
#pragma unroll
    for (int j = 0; j < 2; j++) {
        int col = wid * 32 + j * 16 + l15;
        float bv = b2[col];
#pragma unroll
        for (int i = 0; i < 2; i++) {
#pragma unroll
            for (int r = 0; r < 4; r++) {
                float v = acc2[i][j][r] + bv;
                v = v > 0.f ? v : 0.f;
                Xs[H2OFF + (i * 16 + quad * 4 + r) * H2STR + col] = f2bf(v);
            }
        }
    }
    __syncthreads();

    // ==== phase 3: GEMM3 (16 x 128) @ (128 x 64) + heads, waves 0,1 only ====
    if (wid < 2) {
        int m0l = wid * 16;
        f32x4 acc3[4];
#pragma unroll
        for (int j = 0; j < 4; j++) acc3[j] = (f32x4){0.f, 0.f, 0.f, 0.f};
        const unsigned short* abase = &Xs[H2OFF + (m0l + l15) * H2STR + quad * 8];
        const unsigned short* bptr = W3p + (size_t)l15 * 32 + quad * 8;
#pragma unroll
        for (int kt = 0; kt < 4; ++kt) {
            bf16x8 a = *(const bf16x8*)(abase + kt * 32);
#pragma unroll
            for (int j = 0; j < 4; j++) {
                bf16x8 b = *(const bf16x8*)(bptr + (kt * H3DIM + j * 16) * 32);
                acc3[j] = __builtin_amdgcn_mfma_f32_16x16x32_bf16(a, b, acc3[j], 0, 0, 0);
            }
        }
        float s1r[4] = {0.f, 0.f, 0.f, 0.f};
        float s2r[4] = {0.f, 0.f, 0.f, 0.f};
#pragma unroll
        for (int j = 0; j < 4; j++) {
            int col = j * 16 + l15;
            float bv = b3[col], wc = Wc[col], wo = Wo[col];
#pragma unroll
            for (int r = 0; r < 4; r++) {
                float v = acc3[j][r] + bv;
                v = v > 0.f ? v : 0.f;
                s1r[r] += v * wc;
                s2r[r] += v * wo;
            }
        }
#pragma unroll
        for (int r = 0; r < 4; r++) {
#pragma unroll
            for (int m = 8; m >= 1; m >>= 1) {
                s1r[r] += __shfl_xor(s1r[r], m, 16);
                s2r[r] += __shfl_xor(s2r[r], m, 16);
            }
        }
        if (l15 == 0) {
            float wc64 = Wc[64], wc65 = Wc[65], wo64 = Wo[64], wo65 = Wo[65];
            float bcv = bc[0], bov = bo[0];
#pragma unroll
            for (int r = 0; r < 4; r++) {
                int rl = m0l + quad * 4 + r;
                int row = row0 + rl;
                float lt = s_lin[rl], f2 = s_fm[rl];
                out[row]          = s1r[r] + lt * wc64 + f2 * wc65 + bcv;
                out[B_ROWS + row] = s2r[r] + lt * wo64 + f2 * wo65 + bov;
            }
        }
    }
}

// ---------------- workspace layout (bytes): only packed weights now ----------------
#define OFF_W1P  ((size_t)0)
#define OFF_W2P  (OFF_W1P + (size_t)S1P * 2)   // 638976
#define OFF_W3P  (OFF_W2P + (size_t)S2P * 2)   // +65536
// total = 720896 bytes

extern "C" void kernel_launch(void* const* d_in, const int* in_sizes, int n_in,
                              void* d_out, int out_size, void* d_ws, size_t ws_size,
                              hipStream_t stream)
{
    const int*   x_cat    = (const int*)d_in[0];
    const float* x_num    = (const float*)d_in[1];
    const float* emb0     = (const float*)d_in[2];
    const float* emb1     = (const float*)d_in[3];
    const float* num_bias = (const float*)d_in[4];
    const float* num_emb  = (const float*)d_in[5];
    const float* W1 = (const float*)d_in[6];
    const float* b1 = (const float*)d_in[7];
    const float* W2 = (const float*)d_in[8];
    const float* b2 = (const float*)d_in[9];
    const float* W3 = (const float*)d_in[10];
    const float* b3 = (const float*)d_in[11];
    const float* Wc = (const float*)d_in[12];
    const float* bc = (const float*)d_in[13];
    const float* Wo = (const float*)d_in[14];
    const float* bo = (const float*)d_in[15];
    float* out = (float*)d_out;

    char* ws = (char*)d_ws;
    unsigned short* W1p = (unsigned short*)(ws + OFF_W1P);
    unsigned short* W2p = (unsigned short*)(ws + OFF_W2P);
    unsigned short* W3p = (unsigned short*)(ws + OFF_W3P);

    repack_weights<<<(S1P + S2P + S3P) / 256, 256, 0, stream>>>(W1, W2, W3, W1p, W2p, W3p);
    deepfm_fused<<<B_ROWS / 32, 256, 0, stream>>>(
        x_cat, x_num, emb0, emb1, num_bias, num_emb,
        W1p, b1, W2p, b2, W3p, b3, Wc, bc, Wo, bo, out);
}